// Round 13
// baseline (146.952 us; speedup 1.0000x reference)
//
#include <hip/hip_runtime.h>
#include <hip/hip_fp16.h>

// Reblur_Net: 3 recurrent modulated DCNv2 passes, C=O=3, K=3, B=4, H=W=512.
// out = (sharp + f1 + f2 + f3) / 4.
//
// Simplest structure (no motion conversion, no prep):
//  to_half : sharp fp32 -> half4 px.
//  pass1-3 : identical fp32-motion DCN passes. Each 256-thread block handles
//            TWO 256-px strips (same image row) with double-buffered LDS:
//            DMA(S0) -> barrier -> [issue DMA(S1) || compute S0] -> barrier
//            (drains S1's DMA via vmcnt) -> compute S1. Hides one motion DMA
//            per pair. Direct half4 feature gathers (both corners of a
//            bilinear row = one 16B dwordx4). Pass 3 folds the 4-way average.

#define HH 512
#define WW 512
#define BATCH 4
#define HWSZ (HH * WW)

union U4 { uint4 u; __half2 h[4]; };
union U2 { uint2 u; __half2 h[2]; };

typedef const __attribute__((address_space(1))) void* gas_t;
typedef __attribute__((address_space(3))) void* las_t;

__global__ __launch_bounds__(256) void to_half_kernel(
    const float* __restrict__ sharp, uint4* __restrict__ dst)
{
    const int i = blockIdx.x * 256 + threadIdx.x;   // pair index over B*HWSZ/2
    const int b = i >> 17;
    const int p = (i & (HWSZ / 2 - 1)) * 2;
    const float* s = sharp + (size_t)b * 3 * HWSZ + p;
    const float2 c0 = *(const float2*)(s);
    const float2 c1 = *(const float2*)(s + HWSZ);
    const float2 c2 = *(const float2*)(s + 2 * HWSZ);
    U4 o;
    o.h[0] = __float22half2_rn(make_float2(c0.x, c1.x));
    o.h[1] = __float22half2_rn(make_float2(c2.x, 0.f));
    o.h[2] = __float22half2_rn(make_float2(c0.y, c1.y));
    o.h[3] = __float22half2_rn(make_float2(c2.y, 0.f));
    dst[i] = o.u;
}

// Bilinear sample of 3 channels at (py,px), modulation m, zero outside.
__device__ __forceinline__ void bilinear3(const char* __restrict__ sb,
                                          float py, float px, float m,
                                          float& o0, float& o1, float& o2)
{
    const float y0f = floorf(py), x0f = floorf(px);
    const float wy = py - y0f, wx = px - x0f;
    const bool vy0 = (y0f >= 0.f) && (y0f <= 511.f);
    const bool vy1 = (y0f >= -1.f) && (y0f <= 510.f);
    const bool vx0 = (x0f >= 0.f) && (x0f <= 511.f);
    const bool vx1 = (x0f >= -1.f) && (x0f <= 510.f);
    const int iy0 = (int)fminf(fmaxf(y0f, 0.f), 511.f);
    const int iy1 = (int)fminf(fmaxf(y0f + 1.f, 0.f), 511.f);
    const int ix0 = (int)fminf(fmaxf(x0f, 0.f), 511.f);
    const int ix1 = (int)fminf(fmaxf(x0f + 1.f, 0.f), 511.f);
    const int lc  = (int)fminf(fmaxf(x0f, 0.f), 510.f);   // pair base column
    const int s0 = ix0 - lc;
    const int s1 = ix1 - lc;

    const float w00 = (vy0 && vx0) ? (1.f - wy) * (1.f - wx) * m : 0.f;
    const float w01 = (vy0 && vx1) ? (1.f - wy) * wx * m : 0.f;
    const float w10 = (vy1 && vx0) ? wy * (1.f - wx) * m : 0.f;
    const float w11 = (vy1 && vx1) ? wy * wx * m : 0.f;

    // Blend corner weights onto the two loaded pixel slots (clamp-safe).
    const float wlo0 = s0 ? 0.f : (s1 ? w00 : w00 + w01);
    const float whi0 = s1 ? (s0 ? w00 + w01 : w01) : 0.f;
    const float wlo1 = s0 ? 0.f : (s1 ? w10 : w10 + w11);
    const float whi1 = s1 ? (s0 ? w10 + w11 : w11) : 0.f;

    U4 ra, rb;
    ra.u = *(const uint4*)(sb + (size_t)(iy0 * WW + lc) * 8);
    rb.u = *(const uint4*)(sb + (size_t)(iy1 * WW + lc) * 8);
    const float2 aL = __half22float2(ra.h[0]);
    const float2 aLz = __half22float2(ra.h[1]);
    const float2 aH = __half22float2(ra.h[2]);
    const float2 aHz = __half22float2(ra.h[3]);
    const float2 bL = __half22float2(rb.h[0]);
    const float2 bLz = __half22float2(rb.h[1]);
    const float2 bH = __half22float2(rb.h[2]);
    const float2 bHz = __half22float2(rb.h[3]);

    o0 = wlo0 * aL.x + whi0 * aH.x + wlo1 * bL.x + whi1 * bH.x;
    o1 = wlo0 * aL.y + whi0 * aH.y + wlo1 * bL.y + whi1 * bH.y;
    o2 = wlo0 * aLz.x + whi0 * aHz.x + wlo1 * bLz.x + whi1 * bHz.x;
}

// Compute one strip's DCN for this thread's pixel. mf points at this
// thread's column (mf = lds + t); plane pl is at mf[pl*256].
__device__ __forceinline__ void dcn_strip(
    const float* __restrict__ mf, const float* __restrict__ sw,
    const char* __restrict__ sb, int y, int x,
    float& acc0, float& acc1, float& acc2)
{
    acc0 = sw[81]; acc1 = sw[82]; acc2 = sw[83];
#pragma unroll
    for (int k = 0; k < 9; ++k) {
        const float dy = mf[(2 * k) * 256];
        const float dx = mf[(2 * k + 1) * 256];
        const float m  = mf[(18 + k) * 256];
        const float py = (float)(y + k / 3 - 1) + dy;
        const float px = (float)(x + k % 3 - 1) + dx;

        float v0, v1, v2;
        bilinear3(sb, py, px, m, v0, v1, v2);
        acc0 += sw[0 * 9 + k] * v0 + sw[1 * 9 + k] * v1 + sw[2 * 9 + k] * v2;
        acc1 += sw[3 * 9 + k] * v0 + sw[4 * 9 + k] * v1 + sw[5 * 9 + k] * v2;
        acc2 += sw[6 * 9 + k] * v0 + sw[7 * 9 + k] * v1 + sw[8 * 9 + k] * v2;
    }
}

// LAST: fold out = (sharp + f1 + f2 + f3)/4 (pass 3).
template <bool LAST>
__global__ __launch_bounds__(256) void dcn_kernel(
    const uint2* __restrict__ src,     // [B][HWSZ] half4 px (current features)
    const float* __restrict__ motion,  // [B,27,H,W] fp32
    const float* __restrict__ wgt,     // 81 floats [o][c][k]
    const float* __restrict__ bias,    // 3 floats
    uint2* __restrict__ dst,           // half4 px (if !LAST)
    const uint2* __restrict__ cS,      // sharp half4 (if LAST)
    const uint2* __restrict__ c1,      // f1 half4 (if LAST)
    float* __restrict__ out)           // [B,3,H,W] planar fp32 (if LAST)
{
    __shared__ __align__(16) float mlds0[27 * 256];   // 27648 B
    __shared__ __align__(16) float mlds1[27 * 256];   // 27648 B
    __shared__ float sw[84];

    const int t = threadIdx.x;
    const int blk = blockIdx.x;              // 2048 (two strips each)
    const int s0i = blk * 2;                 // even strip id
    const int b = s0i >> 10;
    const int pb0 = (s0i & 1023) * 256;      // multiple of 512 -> x base 0
    const int pb1 = pb0 + 256;               // same row, x base 256
    const int y = pb0 >> 9;
    const int w = t >> 6, lane = t & 63;

    if (t < 84) sw[t] = (t < 81) ? wgt[t] : bias[t - 81];

    const float* mbase = motion + (size_t)b * 27 * HWSZ;

    // DMA strip S0's motion -> mlds0 (27 planes x 1024 B).
#pragma unroll
    for (int r = 0; r < 7; ++r) {
        const int pl = r * 4 + w;
        if (pl < 27) {
            __builtin_amdgcn_global_load_lds(
                (gas_t)(mbase + (size_t)pl * HWSZ + pb0 + lane * 4),
                (las_t)(mlds0 + pl * 256), 16, 0, 0);
        }
    }

    __syncthreads();   // mlds0 ready (drains vmcnt)

    // Issue strip S1's DMA now; it completes under S0's compute and is
    // guaranteed done by the next __syncthreads (vmcnt drain).
#pragma unroll
    for (int r = 0; r < 7; ++r) {
        const int pl = r * 4 + w;
        if (pl < 27) {
            __builtin_amdgcn_global_load_lds(
                (gas_t)(mbase + (size_t)pl * HWSZ + pb1 + lane * 4),
                (las_t)(mlds1 + pl * 256), 16, 0, 0);
        }
    }

    const uint2* simg = src + ((size_t)b << 18);
    const char* sb = (const char*)simg;
    const int p0 = pb0 + t, p1 = pb1 + t;

    // Center values for the LAST fold (issued early, consumed late).
    U2 cs0, c10, c20, cs1, c11, c21;
    if (LAST) {
        cs0 = *(const U2*)&cS[((size_t)b << 18) + p0];
        c10 = *(const U2*)&c1[((size_t)b << 18) + p0];
        c20 = *(const U2*)&simg[p0];
        cs1 = *(const U2*)&cS[((size_t)b << 18) + p1];
        c11 = *(const U2*)&c1[((size_t)b << 18) + p1];
        c21 = *(const U2*)&simg[p1];
    }

    // ---- compute strip S0 ----
    float a0, a1, a2;
    dcn_strip(mlds0 + t, sw, sb, y, t, a0, a1, a2);

    if (!LAST) {
        U2 o;
        o.h[0] = __float22half2_rn(make_float2(a0, a1));
        o.h[1] = __float22half2_rn(make_float2(a2, 0.f));
        dst[((size_t)b << 18) + p0] = o.u;
    } else {
        const float2 s01 = __half22float2(cs0.h[0]);
        const float2 s2  = __half22float2(cs0.h[1]);
        const float2 f101 = __half22float2(c10.h[0]);
        const float2 f12  = __half22float2(c10.h[1]);
        const float2 f201 = __half22float2(c20.h[0]);
        const float2 f22  = __half22float2(c20.h[1]);
        const size_t ob = (size_t)b * 3 * HWSZ + p0;
        out[ob]            = (s01.x + f101.x + f201.x + a0) * 0.25f;
        out[ob + HWSZ]     = (s01.y + f101.y + f201.y + a1) * 0.25f;
        out[ob + 2 * HWSZ] = (s2.x  + f12.x  + f22.x  + a2) * 0.25f;
    }

    __syncthreads();   // drains S1's DMA (vmcnt) -> mlds1 ready

    // ---- compute strip S1 ----
    float b0, b1, b2;
    dcn_strip(mlds1 + t, sw, sb, y, 256 + t, b0, b1, b2);

    if (!LAST) {
        U2 o;
        o.h[0] = __float22half2_rn(make_float2(b0, b1));
        o.h[1] = __float22half2_rn(make_float2(b2, 0.f));
        dst[((size_t)b << 18) + p1] = o.u;
    } else {
        const float2 s01 = __half22float2(cs1.h[0]);
        const float2 s2  = __half22float2(cs1.h[1]);
        const float2 f101 = __half22float2(c11.h[0]);
        const float2 f12  = __half22float2(c11.h[1]);
        const float2 f201 = __half22float2(c21.h[0]);
        const float2 f22  = __half22float2(c21.h[1]);
        const size_t ob = (size_t)b * 3 * HWSZ + p1;
        out[ob]            = (s01.x + f101.x + f201.x + b0) * 0.25f;
        out[ob + HWSZ]     = (s01.y + f101.y + f201.y + b1) * 0.25f;
        out[ob + 2 * HWSZ] = (s2.x  + f12.x  + f22.x  + b2) * 0.25f;
    }
}

extern "C" void kernel_launch(void* const* d_in, const int* in_sizes, int n_in,
                              void* d_out, int out_size, void* d_ws, size_t ws_size,
                              hipStream_t stream) {
    const float* sharp  = (const float*)d_in[0];
    const float* motion = (const float*)d_in[1];
    const float* wts    = (const float*)d_in[2];  // 3 x 81
    const float* bias   = (const float*)d_in[3];  // 3 x 3
    float* out = (float*)d_out;

    const size_t img = (size_t)BATCH * HWSZ;
    uint2* bufS = (uint2*)d_ws;                   // 8.39 MB each
    uint2* buf1 = bufS + img;
    uint2* buf2 = buf1 + img;

    const dim3 block(256);
    const dim3 gridT(img / 512);                  // 2048
    const dim3 gridD(img / 512);                  // 2048 (2 strips per block)

    to_half_kernel<<<gridT, block, 0, stream>>>(sharp, (uint4*)bufS);
    dcn_kernel<false><<<gridD, block, 0, stream>>>(
        bufS, motion, wts, bias, buf1, nullptr, nullptr, nullptr);
    dcn_kernel<false><<<gridD, block, 0, stream>>>(
        buf1, motion, wts + 81, bias + 3, buf2, nullptr, nullptr, nullptr);
    dcn_kernel<true><<<gridD, block, 0, stream>>>(
        buf2, motion, wts + 162, bias + 6, nullptr, bufS, buf1, out);
}

// Round 14
// 121.296 us; speedup vs baseline: 1.2115x; 1.2115x over previous
//
#include <hip/hip_runtime.h>
#include <hip/hip_fp16.h>

// Reblur_Net: 3 recurrent modulated DCNv2 passes, C=O=3, K=3, B=4, H=W=512.
// out = (sharp + f1 + f2 + f3) / 4.
//
//  to_half : sharp fp32 -> half4 px.
//  pass1   : fp32 motion strip DMA'd to LDS; direct half4 feature gathers;
//            fp16 planar motion repack fused (after the tap loop so gathers
//            start immediately post-barrier).
//  pass2/3 : fp16 motion, TWO strips per block with double-buffered LDS
//            (14.3 KB x 2 = 28.7 KB -> ~5 blocks/CU): DMA(S0) -> barrier ->
//            [issue DMA(S1) || compute S0] -> barrier -> compute S1.
//            Pass 3 folds the 4-way average.

#define HH 512
#define WW 512
#define BATCH 4
#define HWSZ (HH * WW)
#define MP 28            // fp16 motion plane stride (27 + 1 pad)

union U4 { uint4 u; __half2 h[4]; };
union U2 { uint2 u; __half2 h[2]; };

typedef const __attribute__((address_space(1))) void* gas_t;
typedef __attribute__((address_space(3))) void* las_t;

__global__ __launch_bounds__(256) void to_half_kernel(
    const float* __restrict__ sharp, uint4* __restrict__ dst)
{
    const int i = blockIdx.x * 256 + threadIdx.x;   // pair index over B*HWSZ/2
    const int b = i >> 17;
    const int p = (i & (HWSZ / 2 - 1)) * 2;
    const float* s = sharp + (size_t)b * 3 * HWSZ + p;
    const float2 c0 = *(const float2*)(s);
    const float2 c1 = *(const float2*)(s + HWSZ);
    const float2 c2 = *(const float2*)(s + 2 * HWSZ);
    U4 o;
    o.h[0] = __float22half2_rn(make_float2(c0.x, c1.x));
    o.h[1] = __float22half2_rn(make_float2(c2.x, 0.f));
    o.h[2] = __float22half2_rn(make_float2(c0.y, c1.y));
    o.h[3] = __float22half2_rn(make_float2(c2.y, 0.f));
    dst[i] = o.u;
}

// Bilinear sample of 3 channels at (py,px), modulation m, zero outside.
__device__ __forceinline__ void bilinear3(const char* __restrict__ sb,
                                          float py, float px, float m,
                                          float& o0, float& o1, float& o2)
{
    const float y0f = floorf(py), x0f = floorf(px);
    const float wy = py - y0f, wx = px - x0f;
    const bool vy0 = (y0f >= 0.f) && (y0f <= 511.f);
    const bool vy1 = (y0f >= -1.f) && (y0f <= 510.f);
    const bool vx0 = (x0f >= 0.f) && (x0f <= 511.f);
    const bool vx1 = (x0f >= -1.f) && (x0f <= 510.f);
    const int iy0 = (int)fminf(fmaxf(y0f, 0.f), 511.f);
    const int iy1 = (int)fminf(fmaxf(y0f + 1.f, 0.f), 511.f);
    const int ix0 = (int)fminf(fmaxf(x0f, 0.f), 511.f);
    const int ix1 = (int)fminf(fmaxf(x0f + 1.f, 0.f), 511.f);
    const int lc  = (int)fminf(fmaxf(x0f, 0.f), 510.f);   // pair base column
    const int s0 = ix0 - lc;
    const int s1 = ix1 - lc;

    const float w00 = (vy0 && vx0) ? (1.f - wy) * (1.f - wx) * m : 0.f;
    const float w01 = (vy0 && vx1) ? (1.f - wy) * wx * m : 0.f;
    const float w10 = (vy1 && vx0) ? wy * (1.f - wx) * m : 0.f;
    const float w11 = (vy1 && vx1) ? wy * wx * m : 0.f;

    // Blend corner weights onto the two loaded pixel slots (clamp-safe).
    const float wlo0 = s0 ? 0.f : (s1 ? w00 : w00 + w01);
    const float whi0 = s1 ? (s0 ? w00 + w01 : w01) : 0.f;
    const float wlo1 = s0 ? 0.f : (s1 ? w10 : w10 + w11);
    const float whi1 = s1 ? (s0 ? w10 + w11 : w11) : 0.f;

    U4 ra, rb;
    ra.u = *(const uint4*)(sb + (size_t)(iy0 * WW + lc) * 8);
    rb.u = *(const uint4*)(sb + (size_t)(iy1 * WW + lc) * 8);
    const float2 aL = __half22float2(ra.h[0]);
    const float2 aLz = __half22float2(ra.h[1]);
    const float2 aH = __half22float2(ra.h[2]);
    const float2 aHz = __half22float2(ra.h[3]);
    const float2 bL = __half22float2(rb.h[0]);
    const float2 bLz = __half22float2(rb.h[1]);
    const float2 bH = __half22float2(rb.h[2]);
    const float2 bHz = __half22float2(rb.h[3]);

    o0 = wlo0 * aL.x + whi0 * aH.x + wlo1 * bL.x + whi1 * bH.x;
    o1 = wlo0 * aL.y + whi0 * aH.y + wlo1 * bL.y + whi1 * bH.y;
    o2 = wlo0 * aLz.x + whi0 * aHz.x + wlo1 * bLz.x + whi1 * bHz.x;
}

// Pass 1: fp32 motion strip -> LDS; gathers; fp16 repack (after taps).
__global__ __launch_bounds__(256) void dcn_pass1(
    const uint2* __restrict__ src,     // sharp half4
    const float* __restrict__ motion,  // [B,27,H,W] fp32
    __half* __restrict__ mot16,        // [B,MP,H,W] fp16 out
    const float* __restrict__ wgt, const float* __restrict__ bias,
    uint2* __restrict__ dst)           // f1 half4
{
    __shared__ __align__(16) char msmem[27 * 1024];
    __shared__ float sw[84];

    const int t = threadIdx.x;
    const int blk = blockIdx.x;              // 4096
    const int b = blk >> 10;
    const int pbase = (blk & 1023) * 256;
    const int y = pbase >> 9;
    const int x = (pbase & 511) + t;
    const int p = pbase + t;
    const int w = t >> 6, lane = t & 63;

    if (t < 84) sw[t] = (t < 81) ? wgt[t] : bias[t - 81];

    {
        const float* mbase = motion + (size_t)b * 27 * HWSZ + pbase;
#pragma unroll
        for (int r = 0; r < 7; ++r) {
            const int pl = r * 4 + w;
            if (pl < 27) {
                __builtin_amdgcn_global_load_lds(
                    (gas_t)(mbase + (size_t)pl * HWSZ + lane * 4),
                    (las_t)(msmem + pl * 1024), 16, 0, 0);
            }
        }
    }

    const uint2* simg = src + ((size_t)b << 18);
    __syncthreads();

    const char* sb = (const char*)simg;
    const float* mf = (const float*)msmem;
    float acc0 = sw[81], acc1 = sw[82], acc2 = sw[83];

#pragma unroll
    for (int k = 0; k < 9; ++k) {
        const float dy = mf[(2 * k) * 256 + t];
        const float dx = mf[(2 * k + 1) * 256 + t];
        const float m  = mf[(18 + k) * 256 + t];
        const float py = (float)(y + k / 3 - 1) + dy;
        const float px = (float)(x + k % 3 - 1) + dx;

        float v0, v1, v2;
        bilinear3(sb, py, px, m, v0, v1, v2);
        acc0 += sw[0 * 9 + k] * v0 + sw[1 * 9 + k] * v1 + sw[2 * 9 + k] * v2;
        acc1 += sw[3 * 9 + k] * v0 + sw[4 * 9 + k] * v1 + sw[5 * 9 + k] * v2;
        acc2 += sw[6 * 9 + k] * v0 + sw[7 * 9 + k] * v1 + sw[8 * 9 + k] * v2;
    }

    U2 o;
    o.h[0] = __float22half2_rn(make_float2(acc0, acc1));
    o.h[1] = __float22half2_rn(make_float2(acc2, 0.f));
    dst[((size_t)b << 18) + p] = o.u;

    // Repack fp32 LDS strip -> fp16 planar global (tail; fire-and-forget).
    {
        __half* obase = mot16 + (size_t)b * MP * HWSZ + pbase;
#pragma unroll
        for (int r = 0; r < 7; ++r) {
            const int pl = r * 4 + w;
            if (pl < 27) {
                const float4 v = *(const float4*)&mf[pl * 256 + lane * 4];
                U2 q;
                q.h[0] = __float22half2_rn(make_float2(v.x, v.y));
                q.h[1] = __float22half2_rn(make_float2(v.z, v.w));
                *(uint2*)(obase + (size_t)pl * HWSZ + lane * 4) = q.u;
            }
        }
    }
}

// Compute one strip's DCN from an fp16 motion LDS buffer.
__device__ __forceinline__ void dcn_strip16(
    const __half* __restrict__ mh, int t, const float* __restrict__ sw,
    const char* __restrict__ sb, int y, int x,
    float& acc0, float& acc1, float& acc2)
{
    acc0 = sw[81]; acc1 = sw[82]; acc2 = sw[83];
#pragma unroll
    for (int k = 0; k < 9; ++k) {
        const float dy = __half2float(mh[(2 * k) * 256 + t]);
        const float dx = __half2float(mh[(2 * k + 1) * 256 + t]);
        const float m  = __half2float(mh[(18 + k) * 256 + t]);
        const float py = (float)(y + k / 3 - 1) + dy;
        const float px = (float)(x + k % 3 - 1) + dx;

        float v0, v1, v2;
        bilinear3(sb, py, px, m, v0, v1, v2);
        acc0 += sw[0 * 9 + k] * v0 + sw[1 * 9 + k] * v1 + sw[2 * 9 + k] * v2;
        acc1 += sw[3 * 9 + k] * v0 + sw[4 * 9 + k] * v1 + sw[5 * 9 + k] * v2;
        acc2 += sw[6 * 9 + k] * v0 + sw[7 * 9 + k] * v1 + sw[8 * 9 + k] * v2;
    }
}

// Issue the fp16 pair-DMA for one strip (14 wave-ops across 4 waves).
__device__ __forceinline__ void dma_strip16(
    const __half* __restrict__ mbase, int pb, char* __restrict__ lds,
    int w, int lane)
{
#pragma unroll
    for (int r = 0; r < 4; ++r) {
        const int q = r * 4 + w;
        if (q < 14) {
            const int pl = 2 * q + (lane >> 5);
            __builtin_amdgcn_global_load_lds(
                (gas_t)(mbase + (size_t)pl * HWSZ + pb + (lane & 31) * 8),
                (las_t)(lds + q * 1024), 16, 0, 0);
        }
    }
}

// Passes 2-3: fp16 motion, 2 strips per block, double-buffered LDS.
// LAST: fold out = (sharp + f1 + f2 + f3)/4.
template <bool LAST>
__global__ __launch_bounds__(256) void dcn_db16(
    const uint2* __restrict__ src,     // current features half4
    const __half* __restrict__ mot16,  // [B,MP,H,W] fp16
    const float* __restrict__ wgt, const float* __restrict__ bias,
    uint2* __restrict__ dst,           // f_i half4 (if !LAST)
    const uint2* __restrict__ cS,      // sharp half4 (if LAST)
    const uint2* __restrict__ c1,      // f1 half4 (if LAST)
    float* __restrict__ out)           // [B,3,H,W] fp32 (if LAST)
{
    __shared__ __align__(16) char mlds0[MP * 256 * 2];   // 14336 B
    __shared__ __align__(16) char mlds1[MP * 256 * 2];   // 14336 B
    __shared__ float sw[84];

    const int t = threadIdx.x;
    const int blk = blockIdx.x;              // 2048 (two strips each)
    const int s0i = blk * 2;
    const int b = s0i >> 10;
    const int pb0 = (s0i & 1023) * 256;      // x base 0 (row start)
    const int pb1 = pb0 + 256;               // same row, x base 256
    const int y = pb0 >> 9;
    const int w = t >> 6, lane = t & 63;

    if (t < 84) sw[t] = (t < 81) ? wgt[t] : bias[t - 81];

    const __half* mbase = mot16 + (size_t)b * MP * HWSZ;

    dma_strip16(mbase, pb0, mlds0, w, lane);
    __syncthreads();                         // S0 ready (drains vmcnt)
    dma_strip16(mbase, pb1, mlds1, w, lane); // completes under S0's compute

    const uint2* simg = src + ((size_t)b << 18);
    const char* sb = (const char*)simg;
    const int p0 = pb0 + t, p1 = pb1 + t;

    U2 cs0, c10, c20, cs1, c11, c21;
    if (LAST) {
        cs0 = *(const U2*)&cS[((size_t)b << 18) + p0];
        c10 = *(const U2*)&c1[((size_t)b << 18) + p0];
        c20 = *(const U2*)&simg[p0];
        cs1 = *(const U2*)&cS[((size_t)b << 18) + p1];
        c11 = *(const U2*)&c1[((size_t)b << 18) + p1];
        c21 = *(const U2*)&simg[p1];
    }

    // ---- strip S0 ----
    float a0, a1, a2;
    dcn_strip16((const __half*)mlds0, t, sw, sb, y, t, a0, a1, a2);

    if (!LAST) {
        U2 o;
        o.h[0] = __float22half2_rn(make_float2(a0, a1));
        o.h[1] = __float22half2_rn(make_float2(a2, 0.f));
        dst[((size_t)b << 18) + p0] = o.u;
    } else {
        const float2 s01 = __half22float2(cs0.h[0]);
        const float2 s2  = __half22float2(cs0.h[1]);
        const float2 f101 = __half22float2(c10.h[0]);
        const float2 f12  = __half22float2(c10.h[1]);
        const float2 f201 = __half22float2(c20.h[0]);
        const float2 f22  = __half22float2(c20.h[1]);
        const size_t ob = (size_t)b * 3 * HWSZ + p0;
        out[ob]            = (s01.x + f101.x + f201.x + a0) * 0.25f;
        out[ob + HWSZ]     = (s01.y + f101.y + f201.y + a1) * 0.25f;
        out[ob + 2 * HWSZ] = (s2.x  + f12.x  + f22.x  + a2) * 0.25f;
    }

    __syncthreads();                         // drains S1's DMA -> ready

    // ---- strip S1 ----
    float b0, b1, b2;
    dcn_strip16((const __half*)mlds1, t, sw, sb, y, 256 + t, b0, b1, b2);

    if (!LAST) {
        U2 o;
        o.h[0] = __float22half2_rn(make_float2(b0, b1));
        o.h[1] = __float22half2_rn(make_float2(b2, 0.f));
        dst[((size_t)b << 18) + p1] = o.u;
    } else {
        const float2 s01 = __half22float2(cs1.h[0]);
        const float2 s2  = __half22float2(cs1.h[1]);
        const float2 f101 = __half22float2(c11.h[0]);
        const float2 f12  = __half22float2(c11.h[1]);
        const float2 f201 = __half22float2(c21.h[0]);
        const float2 f22  = __half22float2(c21.h[1]);
        const size_t ob = (size_t)b * 3 * HWSZ + p1;
        out[ob]            = (s01.x + f101.x + f201.x + b0) * 0.25f;
        out[ob + HWSZ]     = (s01.y + f101.y + f201.y + b1) * 0.25f;
        out[ob + 2 * HWSZ] = (s2.x  + f12.x  + f22.x  + b2) * 0.25f;
    }
}

extern "C" void kernel_launch(void* const* d_in, const int* in_sizes, int n_in,
                              void* d_out, int out_size, void* d_ws, size_t ws_size,
                              hipStream_t stream) {
    const float* sharp  = (const float*)d_in[0];
    const float* motion = (const float*)d_in[1];
    const float* wts    = (const float*)d_in[2];  // 3 x 81
    const float* bias   = (const float*)d_in[3];  // 3 x 3
    float* out = (float*)d_out;

    const size_t img = (size_t)BATCH * HWSZ;
    uint2* bufS = (uint2*)d_ws;                   // 8.39 MB each
    uint2* buf1 = bufS + img;
    uint2* buf2 = buf1 + img;
    __half* mot16 = (__half*)(buf2 + img);        // 58.7 MB

    const dim3 block(256);
    const dim3 gridT(img / 512);                  // 2048
    const dim3 grid1(img / 256);                  // 4096
    const dim3 gridD(img / 512);                  // 2048 (2 strips/block)

    to_half_kernel<<<gridT, block, 0, stream>>>(sharp, (uint4*)bufS);
    dcn_pass1<<<grid1, block, 0, stream>>>(
        bufS, motion, mot16, wts, bias, buf1);
    dcn_db16<false><<<gridD, block, 0, stream>>>(
        buf1, mot16, wts + 81, bias + 3, buf2, nullptr, nullptr, nullptr);
    dcn_db16<true><<<gridD, block, 0, stream>>>(
        buf2, mot16, wts + 162, bias + 6, nullptr, bufS, buf1, out);
}